// Round 4
// baseline (1006.556 us; speedup 1.0000x reference)
//
#include <hip/hip_runtime.h>
#include <cstdint>

#define T_STEPS 128
#define BATCH   1024
#define D_INPUT 96
#define H_DIM   128
#define NWIN    163   // 121 full 7-frame windows + 6 prefix partials + 36 clipped partials
#define BD      (BATCH * D_INPUT)   // 98304 floats per time frame

// (t, s) -> widx, or -1 when the reference window is empty (cur1 == +0)
__device__ __forceinline__ int widx_for(int t, int s) {
    if (t >= 49) return t - 49 + 7 * s;                 // slide regime: full windows
    if (s == 0)  return 121 + min(5, t);                // [0, min(5,t)]
    const int st = 7 * s - 1;
    if (t < st) return -1;
    const int len = min(7, t - st + 1);
    return (len == 7) ? st : (127 + (s - 1) * 6 + (len - 1));
}

// XOR swizzle keeping even/odd float2 pairs adjacent and 8B-aligned
__device__ __forceinline__ int swz_idx(int row, int col) {
    return (row << 7) | (col ^ ((row & 63) << 1));
}

// ---------------------------------------------------------------------------
// kT: one-shot weight reshapes.
//   blocks 0..47  : Win (128x96)  -> WinT (96x128)
//   blocks 48..111: Wh0 (128x128) -> Wh0P packed per (j,lane):
//     Wh0P[(j*64+l)*4 + {0,1,2,3}] = { Wh0[2l][2j], Wh0[2l+1][2j],
//                                      Wh0[2l][2j+1], Wh0[2l+1][2j+1] }
//   so kB's inner loop fetches its full (we.x,we.y,wo.x,wo.y) as ONE
//   coalesced float4 per lane per j (halves VMEM instructions).
// ---------------------------------------------------------------------------
__global__ __launch_bounds__(256) void kT_wint(const float* __restrict__ Win,
                                               const float* __restrict__ Wh0,
                                               float* __restrict__ WinT,
                                               float* __restrict__ Wh0P) {
    const int tid = threadIdx.x;
    if (blockIdx.x < 48) {
        const int e = blockIdx.x * 256 + tid;           // < 128*96
        const int h = e / D_INPUT, d = e % D_INPUT;
        WinT[d * H_DIM + h] = Win[e];
    } else {
        const int e = (blockIdx.x - 48) * 256 + tid;    // < 64*64*4 = 16384
        const int f = e & 3, l = (e >> 2) & 63, j = e >> 8;
        const int i = 2 * l + (f & 1);
        const int h = 2 * j + (f >> 1);
        Wh0P[e] = Wh0[i * H_DIM + h];
    }
}

// ---------------------------------------------------------------------------
// kA0: one streaming pass over x. Thread <-> (b,d); 7-frame ring in registers
// (t-loop fully unrolled -> all ring indices compile-time -> no scratch).
// Emits every window sum with the EXACT ascending-frame __fadd_rn chain the
// validated win_decode windows used. x read once (50 MB), WS written once.
// ---------------------------------------------------------------------------
__global__ __launch_bounds__(256) void kA0_winsum(const float* __restrict__ x,
                                                  float* __restrict__ WS) {
    const int flat = blockIdx.x * 256 + threadIdx.x;    // b*96 + d
    float* wsp = WS + flat;
    float r[7];
#pragma unroll
    for (int t = 0; t < T_STEPS; ++t) {
        r[t % 7] = x[(size_t)t * BD + flat];
        if (t <= 5) {                                   // s0 prefix, len = t+1
            float s = r[0];
#pragma unroll
            for (int k = 1; k <= t; ++k) s = __fadd_rn(s, r[k % 7]);
            wsp[(size_t)(121 + t) * BD] = s;
        }
        if (t >= 6 && t <= 126) {                       // full window w = t-6
            const int w = t - 6;
            float s = r[w % 7];
#pragma unroll
            for (int k = 1; k < 7; ++k) s = __fadd_rn(s, r[(w + k) % 7]);
            wsp[(size_t)w * BD] = s;
        }
        if (t >= 6 && t <= 46) {                        // grow partial (<=1 per t)
            const int sv = (t + 1) / 7;
            if (sv >= 1 && 7 * sv >= t - 4 && 7 * sv <= t + 1) {
                const int start = 7 * sv - 1;
                const int len = t - start + 1;          // 1..6 by construction
                float s = r[start % 7];
#pragma unroll
                for (int k = 1; k < len; ++k) s = __fadd_rn(s, r[(start + k) % 7]);
                wsp[(size_t)(127 + (sv - 1) * 6 + (len - 1)) * BD] = s;
            }
        }
    }
}

// ---------------------------------------------------------------------------
// kA1: CUR1[widx][b][h] = seqFMA_{d}( WS[widx][b][d], Win[h][d] ) — compute
// loop and output layout byte-identical to the validated kernel (ascending-d
// single-acc fmaf), so CUR1 is bit-identical and kB sees identical inputs.
// UNCHANGED this round.
// ---------------------------------------------------------------------------
__global__ __launch_bounds__(256) void kA_wincur(const float* __restrict__ WS,
                                                 const float* __restrict__ WinT,
                                                 float* __restrict__ CUR1) {
    __shared__ float xs[D_INPUT * 32];                  // xs[d*32 + bq], 12 KB
    __shared__ float wT[D_INPUT * H_DIM];               // 48 KB, wT[swz_idx(d,h)]
    const int widx = blockIdx.x;
    const int b0   = blockIdx.y * 32;
    const int tid  = threadIdx.x;

    {
        const float2* WinT2 = (const float2*)WinT;
        for (int e2 = tid; e2 < D_INPUT * (H_DIM / 2); e2 += 256) {
            const int d = e2 >> 6, h2 = e2 & 63;
            *(float2*)&wT[swz_idx(d, h2 << 1)] = WinT2[e2];
        }
    }
    for (int e = tid; e < D_INPUT * 32; e += 256) {
        const int d = e % D_INPUT, bq = e / D_INPUT;
        xs[d * 32 + bq] = WS[(size_t)widx * BD + (size_t)(b0 + bq) * D_INPUT + d];
    }
    __syncthreads();

    const int hp = tid & 63, g = tid >> 6;              // h-pair; wave -> b-octet
    const int h0 = hp << 1;
    float acc[8][2];
#pragma unroll
    for (int r = 0; r < 8; ++r) { acc[r][0] = 0.f; acc[r][1] = 0.f; }

#pragma unroll 6
    for (int d = 0; d < D_INPUT; ++d) {                 // ascending d, one acc each (exact)
        const float2 wp  = *(const float2*)&wT[swz_idx(d, h0)];      // ds_read_b64
        const float4 xv0 = *(const float4*)&xs[d * 32 + g * 8];      // broadcast b128
        const float4 xv1 = *(const float4*)&xs[d * 32 + g * 8 + 4];
        const float xv[8] = {xv0.x,xv0.y,xv0.z,xv0.w, xv1.x,xv1.y,xv1.z,xv1.w};
#pragma unroll
        for (int r = 0; r < 8; ++r) {
            acc[r][0] = __fmaf_rn(xv[r], wp.x, acc[r][0]);
            acc[r][1] = __fmaf_rn(xv[r], wp.y, acc[r][1]);
        }
    }
    float* op = CUR1 + ((size_t)widx * BATCH + b0 + g * 8) * H_DIM + h0;
#pragma unroll
    for (int r = 0; r < 8; ++r) {
        float2 o; o.x = acc[r][0]; o.y = acc[r][1];
        *(float2*)(op + (size_t)r * H_DIM) = o;
    }
}

// ---------------------------------------------------------------------------
// kB: 7 SNN steps, 16 (t,b) pairs per wave.
// ROUND-4 CHANGE (theory: LDS data-path bound on broadcast spike reads —
// r1 vs r3 showed doubling waves didn't help, so the shared LDS unit was
// saturated: 8x ds_read_b128 broadcast/j = ~96 LDS-cyc vs 32W VALU-cyc).
// Spikes now published as 16-BIT TOKENS 0x3F80/0x0000 = high half of the
// f32 bit pattern of 1.0f. Per j: FOUR b128 broadcast reads (64B) instead
// of eight (128B), and unpack is ONE VALU op per value:
//   f[2m]   = asfloat(word << 16)        -> exactly 1.0f or 0.0f
//   f[2m+1] = asfloat(word & 0xFFFF0000) -> exactly 1.0f or 0.0f
// so the spike VALUES feeding the fma chain are bit-identical. Weights come
// as one coalesced float4/lane/j from the packed L2-resident Wh0P.
// sf shrinks 64 KB -> 32 KB. Publish uses 16B-chunk XOR swizzle
// (c ^ ((lane>>1)&3)) -> 8-way write conflict (vs 32-way unswizzled);
// publish is 4 instr/s/wave — negligible vs the 64-j read loop.
// fma order, weight values, spike values, membrane arithmetic: unchanged.
// ---------------------------------------------------------------------------
__global__ __launch_bounds__(512, 2) void kB_snn(const float* __restrict__ CUR1,
                                                 const float* __restrict__ Wh0P,
                                                 const float* __restrict__ Wout,
                                                 const float* __restrict__ vxp,
                                                 const float* __restrict__ vyp,
                                                 float* __restrict__ out) {
    __shared__ uint32_t sf[8][1024];                    // 32 KB: per-wave token strips
    const int tid = threadIdx.x;

    const int w = tid >> 6, lane = tid & 63;
    const int t  = blockIdx.y;
    const int i0 = lane << 1;
    uint32_t* sfu = sf[w];
    const float wex = Wout[i0],     wey = Wout[H_DIM + i0];
    const float wox = Wout[i0 + 1], woy = Wout[H_DIM + i0 + 1];
    const float vx = vxp[0], vy = vyp[0];
    const int b0 = (blockIdx.x << 7) + (w << 4);        // 16 consecutive b per wave
    const int swl = (lane >> 1) & 3;                    // publish chunk swizzle
    uint32_t* pub = sfu + lane * 16;                    // 16 words = 64B strip

    float m1a[16], m1b[16], m2a[16], m2b[16], poa[16], pob[16];
    float c1a[16], c1b[16];
    bool  s1a[16], s1b[16], s2a[16], s2b[16];
#pragma unroll
    for (int k = 0; k < 16; ++k) {
        m1a[k]=0.f; m1b[k]=0.f; m2a[k]=0.f; m2b[k]=0.f; poa[k]=0.f; pob[k]=0.f;
        s1a[k]=false; s1b[k]=false; s2a[k]=false; s2b[k]=false;
    }

    // load cur1 for s = 0
    {
        const int wi = widx_for(t, 0);
#pragma unroll
        for (int k = 0; k < 16; ++k) {
            c1a[k] = 0.f; c1b[k] = 0.f;
            if (wi >= 0) {
                const float2 v = *(const float2*)
                    &CUR1[((size_t)wi * BATCH + b0 + k) * H_DIM + i0];
                c1a[k] = v.x; c1b[k] = v.y;
            }
        }
    }

#pragma unroll 1
    for (int s = 0; s < 7; ++s) {
        // ---- mem1 update + spike tokens (exact), publish to sf -------------
        uint32_t tok[16];                               // words 0..7 = se pairs, 8..15 = so
#pragma unroll
        for (int m = 0; m < 8; ++m) {
            float na0 = __fadd_rn(__fmul_rn(0.9f, m1a[2*m  ]), c1a[2*m  ]);
            float nb0 = __fadd_rn(__fmul_rn(0.9f, m1b[2*m  ]), c1b[2*m  ]);
            float na1 = __fadd_rn(__fmul_rn(0.9f, m1a[2*m+1]), c1a[2*m+1]);
            float nb1 = __fadd_rn(__fmul_rn(0.9f, m1b[2*m+1]), c1b[2*m+1]);
            m1a[2*m  ] = s1a[2*m  ] ? 0.f : na0;
            m1b[2*m  ] = s1b[2*m  ] ? 0.f : nb0;
            m1a[2*m+1] = s1a[2*m+1] ? 0.f : na1;
            m1b[2*m+1] = s1b[2*m+1] ? 0.f : nb1;
            s1a[2*m  ] = m1a[2*m  ] > 0.5f;  s1b[2*m  ] = m1b[2*m  ] > 0.5f;
            s1a[2*m+1] = m1a[2*m+1] > 0.5f;  s1b[2*m+1] = m1b[2*m+1] > 0.5f;
            const uint32_t t0 = s1a[2*m  ] ? 0x3F80u : 0u;
            const uint32_t t1 = s1a[2*m+1] ? 0x3F80u : 0u;
            const uint32_t u0 = s1b[2*m  ] ? 0x3F80u : 0u;
            const uint32_t u1 = s1b[2*m+1] ? 0x3F80u : 0u;
            tok[m]     = t0 | (t1 << 16);
            tok[8 + m] = u0 | (u1 << 16);
        }
#pragma unroll
        for (int c = 0; c < 4; ++c) {
            uint4 v;
            v.x = tok[c*4]; v.y = tok[c*4+1]; v.z = tok[c*4+2]; v.w = tok[c*4+3];
            *(uint4*)&pub[((c ^ swl) << 2)] = v;
        }

        // ---- prefetch next step's cur1 into the now-dead c1 registers ------
        const int win = (s < 6) ? widx_for(t, s + 1) : -1;
#pragma unroll
        for (int k = 0; k < 16; ++k) {
            c1a[k] = 0.f; c1b[k] = 0.f;
            if (win >= 0) {
                const float2 v = *(const float2*)
                    &CUR1[((size_t)win * BATCH + b0 + k) * H_DIM + i0];
                c1a[k] = v.x; c1b[k] = v.y;
            }
        }

        // ---- dense cur2: ascending h, fma with broadcast spike tokens ------
        float c2a[16], c2b[16];
#pragma unroll
        for (int k = 0; k < 16; ++k) { c2a[k] = 0.f; c2b[k] = 0.f; }
#pragma unroll 8
        for (int j = 0; j < 64; ++j) {
            // one coalesced float4: (we.x, we.y, wo.x, wo.y)
            const float4 wv = *(const float4*)&Wh0P[((size_t)j * 64 + lane) * 4];
            const int swj = (j >> 1) & 3;
            const uint32_t* pj = sfu + j * 16;
            const uint4 q0 = *(const uint4*)&pj[((0 ^ swj) << 2)];
            const uint4 q1 = *(const uint4*)&pj[((1 ^ swj) << 2)];
            const uint4 q2 = *(const uint4*)&pj[((2 ^ swj) << 2)];
            const uint4 q3 = *(const uint4*)&pj[((3 ^ swj) << 2)];
            const uint32_t wd[16] = {q0.x,q0.y,q0.z,q0.w, q1.x,q1.y,q1.z,q1.w,
                                     q2.x,q2.y,q2.z,q2.w, q3.x,q3.y,q3.z,q3.w};
            float se[16], so[16];
#pragma unroll
            for (int m = 0; m < 8; ++m) {
                se[2*m  ] = __uint_as_float(wd[m]     << 16);
                se[2*m+1] = __uint_as_float(wd[m]     & 0xFFFF0000u);
                so[2*m  ] = __uint_as_float(wd[8 + m] << 16);
                so[2*m+1] = __uint_as_float(wd[8 + m] & 0xFFFF0000u);
            }
#pragma unroll
            for (int k = 0; k < 16; ++k) {
                c2a[k] = __fmaf_rn(se[k], wv.x, c2a[k]);   // h = 2j
                c2b[k] = __fmaf_rn(se[k], wv.y, c2b[k]);
                c2a[k] = __fmaf_rn(so[k], wv.z, c2a[k]);   // h = 2j+1
                c2b[k] = __fmaf_rn(so[k], wv.w, c2b[k]);
            }
        }

        // ---- mem2 + spikes (exact) and linear output tail (relaxed) --------
#pragma unroll
        for (int k = 0; k < 16; ++k) {
            m2a[k] = s2a[k] ? 0.f : __fadd_rn(__fmul_rn(0.9f, m2a[k]), c2a[k]);
            m2b[k] = s2b[k] ? 0.f : __fadd_rn(__fmul_rn(0.9f, m2b[k]), c2b[k]);
            s2a[k] = m2a[k] > 0.5f; s2b[k] = m2b[k] > 0.5f;
            const float p0 = (s2a[k] ? wex : 0.f) + (s2b[k] ? wox : 0.f);
            const float p1 = (s2a[k] ? wey : 0.f) + (s2b[k] ? woy : 0.f);
            poa[k] = __fmaf_rn(0.9f, poa[k], p0);       // mem_out is linear: order-safe
            pob[k] = __fmaf_rn(0.9f, pob[k], p1);
        }
    }

    // ---- reduce per-lane output partials, write -----------------------------
#pragma unroll
    for (int k = 0; k < 16; ++k) {
        float r0 = poa[k], r1 = pob[k];
#pragma unroll
        for (int off = 32; off > 0; off >>= 1) {
            r0 += __shfl_xor(r0, off);
            r1 += __shfl_xor(r1, off);
        }
        if (lane == 0) {
            float2 o;
            o.x = __fmul_rn(r0, vx);
            o.y = __fmul_rn(r1, vy);
            *(float2*)(out + ((size_t)t * BATCH + b0 + k) * 2) = o;
        }
    }
}

// ---------------------------------------------------------------------------
extern "C" void kernel_launch(void* const* d_in, const int* in_sizes, int n_in,
                              void* d_out, int out_size, void* d_ws, size_t ws_size,
                              hipStream_t stream) {
    const float* x    = (const float*)d_in[0];   // (128,1024,96)
    const float* Win  = (const float*)d_in[1];   // (128,96)
    const float* Wh0  = (const float*)d_in[2];   // (128,128)
    const float* Wout = (const float*)d_in[3];   // (2,128)
    const float* vx   = (const float*)d_in[4];   // (1,)
    const float* vy   = (const float*)d_in[5];   // (1,)
    float* out  = (float*)d_out;                 // (128,1024,2)

    // workspace: CUR1 (85.5 MB) | WS (64.1 MB) | WinT (48 KB) | Wh0P (64 KB)
    float* CUR1 = (float*)d_ws;
    float* WS   = CUR1 + (size_t)NWIN * BATCH * H_DIM;
    float* WinT = WS   + (size_t)NWIN * BATCH * D_INPUT;
    float* Wh0P = WinT + (size_t)D_INPUT * H_DIM;

    kT_wint   <<<dim3(112),                 dim3(256), 0, stream>>>(Win, Wh0, WinT, Wh0P);
    kA0_winsum<<<dim3(BD / 256),            dim3(256), 0, stream>>>(x, WS);
    kA_wincur <<<dim3(NWIN, BATCH / 32),    dim3(256), 0, stream>>>(WS, WinT, CUR1);
    kB_snn    <<<dim3(BATCH / 128, T_STEPS), dim3(512), 0, stream>>>(CUR1, Wh0P, Wout, vx, vy, out);
}

// Round 5
// 828.912 us; speedup vs baseline: 1.2143x; 1.2143x over previous
//
#include <hip/hip_runtime.h>
#include <cstdint>

#define T_STEPS 128
#define BATCH   1024
#define D_INPUT 96
#define H_DIM   128
#define NWIN    163   // 121 full 7-frame windows + 6 prefix partials + 36 clipped partials
#define BD      (BATCH * D_INPUT)   // 98304 floats per time frame

// (t, s) -> widx, or -1 when the reference window is empty (cur1 == +0)
__device__ __forceinline__ int widx_for(int t, int s) {
    if (t >= 49) return t - 49 + 7 * s;                 // slide regime: full windows
    if (s == 0)  return 121 + min(5, t);                // [0, min(5,t)]
    const int st = 7 * s - 1;
    if (t < st) return -1;
    const int len = min(7, t - st + 1);
    return (len == 7) ? st : (127 + (s - 1) * 6 + (len - 1));
}

// XOR swizzle keeping even/odd float2 pairs adjacent and 8B-aligned
__device__ __forceinline__ int swz_idx(int row, int col) {
    return (row << 7) | (col ^ ((row & 63) << 1));
}

// ---------------------------------------------------------------------------
// kT: one-shot weight reshapes.
//   blocks 0..47  : Win (128x96)  -> WinT (96x128)
//   blocks 48..111: Wh0 (128x128) -> Wh0Q packed per (j, i-quad q):
//     Wh0Q[((j*32+q)*2+p)*4 + r] = Wh0[(4q+r)*128 + (2j+p)]
//   so kB's lane (i-quad q) fetches w[h=2j][i=4q..4q+3] and w[h=2j+1][...]
//   as TWO coalesced float4 loads per j from the L2-resident 64 KB table.
// ---------------------------------------------------------------------------
__global__ __launch_bounds__(256) void kT_wint(const float* __restrict__ Win,
                                               const float* __restrict__ Wh0,
                                               float* __restrict__ WinT,
                                               float* __restrict__ Wh0Q) {
    const int tid = threadIdx.x;
    if (blockIdx.x < 48) {
        const int e = blockIdx.x * 256 + tid;           // < 128*96
        const int h = e / D_INPUT, d = e % D_INPUT;
        WinT[d * H_DIM + h] = Win[e];
    } else {
        const int e = (blockIdx.x - 48) * 256 + tid;    // < 64*32*2*4 = 16384
        const int r = e & 3, p = (e >> 2) & 1, q = (e >> 3) & 31, j = e >> 8;
        Wh0Q[e] = Wh0[(4 * q + r) * H_DIM + (2 * j + p)];
    }
}

// ---------------------------------------------------------------------------
// kA0: one streaming pass over x. Thread <-> (b,d); 7-frame ring in registers
// (t-loop fully unrolled -> all ring indices compile-time -> no scratch).
// Emits every window sum with the EXACT ascending-frame __fadd_rn chain the
// validated win_decode windows used. x read once (50 MB), WS written once.
// ---------------------------------------------------------------------------
__global__ __launch_bounds__(256) void kA0_winsum(const float* __restrict__ x,
                                                  float* __restrict__ WS) {
    const int flat = blockIdx.x * 256 + threadIdx.x;    // b*96 + d
    float* wsp = WS + flat;
    float r[7];
#pragma unroll
    for (int t = 0; t < T_STEPS; ++t) {
        r[t % 7] = x[(size_t)t * BD + flat];
        if (t <= 5) {                                   // s0 prefix, len = t+1
            float s = r[0];
#pragma unroll
            for (int k = 1; k <= t; ++k) s = __fadd_rn(s, r[k % 7]);
            wsp[(size_t)(121 + t) * BD] = s;
        }
        if (t >= 6 && t <= 126) {                       // full window w = t-6
            const int w = t - 6;
            float s = r[w % 7];
#pragma unroll
            for (int k = 1; k < 7; ++k) s = __fadd_rn(s, r[(w + k) % 7]);
            wsp[(size_t)w * BD] = s;
        }
        if (t >= 6 && t <= 46) {                        // grow partial (<=1 per t)
            const int sv = (t + 1) / 7;
            if (sv >= 1 && 7 * sv >= t - 4 && 7 * sv <= t + 1) {
                const int start = 7 * sv - 1;
                const int len = t - start + 1;          // 1..6 by construction
                float s = r[start % 7];
#pragma unroll
                for (int k = 1; k < len; ++k) s = __fadd_rn(s, r[(start + k) % 7]);
                wsp[(size_t)(127 + (sv - 1) * 6 + (len - 1)) * BD] = s;
            }
        }
    }
}

// ---------------------------------------------------------------------------
// kA1: CUR1[widx][b][h] = seqFMA_{d}( WS[widx][b][d], Win[h][d] ) — compute
// loop and output layout byte-identical to the validated kernel (ascending-d
// single-acc fmaf), so CUR1 is bit-identical and kB sees identical inputs.
// UNCHANGED this round.
// ---------------------------------------------------------------------------
__global__ __launch_bounds__(256) void kA_wincur(const float* __restrict__ WS,
                                                 const float* __restrict__ WinT,
                                                 float* __restrict__ CUR1) {
    __shared__ float xs[D_INPUT * 32];                  // xs[d*32 + bq], 12 KB
    __shared__ float wT[D_INPUT * H_DIM];               // 48 KB, wT[swz_idx(d,h)]
    const int widx = blockIdx.x;
    const int b0   = blockIdx.y * 32;
    const int tid  = threadIdx.x;

    {
        const float2* WinT2 = (const float2*)WinT;
        for (int e2 = tid; e2 < D_INPUT * (H_DIM / 2); e2 += 256) {
            const int d = e2 >> 6, h2 = e2 & 63;
            *(float2*)&wT[swz_idx(d, h2 << 1)] = WinT2[e2];
        }
    }
    for (int e = tid; e < D_INPUT * 32; e += 256) {
        const int d = e % D_INPUT, bq = e / D_INPUT;
        xs[d * 32 + bq] = WS[(size_t)widx * BD + (size_t)(b0 + bq) * D_INPUT + d];
    }
    __syncthreads();

    const int hp = tid & 63, g = tid >> 6;              // h-pair; wave -> b-octet
    const int h0 = hp << 1;
    float acc[8][2];
#pragma unroll
    for (int r = 0; r < 8; ++r) { acc[r][0] = 0.f; acc[r][1] = 0.f; }

#pragma unroll 6
    for (int d = 0; d < D_INPUT; ++d) {                 // ascending d, one acc each (exact)
        const float2 wp  = *(const float2*)&wT[swz_idx(d, h0)];      // ds_read_b64
        const float4 xv0 = *(const float4*)&xs[d * 32 + g * 8];      // broadcast b128
        const float4 xv1 = *(const float4*)&xs[d * 32 + g * 8 + 4];
        const float xv[8] = {xv0.x,xv0.y,xv0.z,xv0.w, xv1.x,xv1.y,xv1.z,xv1.w};
#pragma unroll
        for (int r = 0; r < 8; ++r) {
            acc[r][0] = __fmaf_rn(xv[r], wp.x, acc[r][0]);
            acc[r][1] = __fmaf_rn(xv[r], wp.y, acc[r][1]);
        }
    }
    float* op = CUR1 + ((size_t)widx * BATCH + b0 + g * 8) * H_DIM + h0;
#pragma unroll
    for (int r = 0; r < 8; ++r) {
        float2 o; o.x = acc[r][0]; o.y = acc[r][1];
        *(float2*)(op + (size_t)r * H_DIM) = o;
    }
}

// ---------------------------------------------------------------------------
// kB: 7 SNN steps, 16 (t,b) pairs per wave.
// ROUND-5 CHANGE (r4 lesson: added VALU bills at full price -> reduce LDS
// instr at ZERO VALU cost). cur2 lane mapping reshaped from (2 i x 16 b) to
// (4 i x 8 b): lane = (g = b-subgroup of 8, q = i-quad). Per j per lane:
//   spikes: FOUR b128 broadcast reads of the lane's own 8-b strip (was 8)
//   weights: TWO coalesced float4 from packed Wh0Q (same VMEM count as r3)
//   fma: 64 (unchanged), raw f32 spikes (no unpack)
// -> LDS broadcast demand halved, VALU at the r3 floor. Per-(b,i) cur2 chain
// is the same ascending-h single-accumulator fma chain -> cur2/mem2/spike
// stream bit-identical. Only the relaxed linear Wout tail changes
// association (4-i lane partials, 32-lane group reduce). mem1 phase,
// spike publish (f32, chunk-swizzled), and c1 prefetch are r3-verbatim.
// ---------------------------------------------------------------------------
__global__ __launch_bounds__(512, 2) void kB_snn(const float* __restrict__ CUR1,
                                                 const float* __restrict__ Wh0Q,
                                                 const float* __restrict__ Wout,
                                                 const float* __restrict__ vxp,
                                                 const float* __restrict__ vyp,
                                                 float* __restrict__ out) {
    __shared__ float sf[8][64 * 32];                    // 64 KB, per-wave spike floats
    const int tid = threadIdx.x;

    const int w = tid >> 6, lane = tid & 63;
    const int t  = blockIdx.y;
    const int i0 = lane << 1;                           // mem1 h-pair (unchanged role)
    const int g  = lane >> 5;                           // cur2: b-subgroup (8 b's)
    const int q  = lane & 31;                           // cur2: i-quad
    const int iq = q << 2;
    float* sfw = sf[w];
    const int lbase = lane * 32;                        // publish strip (h-pair = lane)
    const float4 wex4 = *(const float4*)&Wout[iq];          // out0, i = iq..iq+3
    const float4 wey4 = *(const float4*)&Wout[H_DIM + iq];  // out1
    const float vx = vxp[0], vy = vyp[0];
    const int b0 = (blockIdx.x << 7) + (w << 4);        // 16 consecutive b per wave

    float m1a[16], m1b[16], c1a[16], c1b[16];
    bool  s1a[16], s1b[16];
    float m2[8][4], po0[8], po1[8];
    bool  s2[8][4];
#pragma unroll
    for (int k = 0; k < 16; ++k) {
        m1a[k]=0.f; m1b[k]=0.f; s1a[k]=false; s1b[k]=false;
    }
#pragma unroll
    for (int b = 0; b < 8; ++b) {
        po0[b]=0.f; po1[b]=0.f;
#pragma unroll
        for (int r = 0; r < 4; ++r) { m2[b][r]=0.f; s2[b][r]=false; }
    }

    // load cur1 for s = 0
    {
        const int wi = widx_for(t, 0);
#pragma unroll
        for (int k = 0; k < 16; ++k) {
            c1a[k] = 0.f; c1b[k] = 0.f;
            if (wi >= 0) {
                const float2 v = *(const float2*)
                    &CUR1[((size_t)wi * BATCH + b0 + k) * H_DIM + i0];
                c1a[k] = v.x; c1b[k] = v.y;
            }
        }
    }

#pragma unroll 1
    for (int s = 0; s < 7; ++s) {
        // ---- mem1 update + spike floats (exact), publish to sf -------------
        float sev[16], sov[16];
#pragma unroll
        for (int k = 0; k < 16; ++k) {
            m1a[k] = s1a[k] ? 0.f : __fadd_rn(__fmul_rn(0.9f, m1a[k]), c1a[k]);
            m1b[k] = s1b[k] ? 0.f : __fadd_rn(__fmul_rn(0.9f, m1b[k]), c1b[k]);
            s1a[k] = m1a[k] > 0.5f; s1b[k] = m1b[k] > 0.5f;
            sev[k] = s1a[k] ? 1.0f : 0.0f;
            sov[k] = s1b[k] ? 1.0f : 0.0f;
        }
        // chunks 0..3 = se[0..15], 4..7 = so[0..15]; chunk swizzled by lane&7
#pragma unroll
        for (int c = 0; c < 4; ++c) {
            float4 v;
            v.x = sev[c*4]; v.y = sev[c*4+1]; v.z = sev[c*4+2]; v.w = sev[c*4+3];
            *(float4*)&sfw[lbase + ((c     ^ (lane & 7)) << 2)] = v;
            v.x = sov[c*4]; v.y = sov[c*4+1]; v.z = sov[c*4+2]; v.w = sov[c*4+3];
            *(float4*)&sfw[lbase + (((c+4) ^ (lane & 7)) << 2)] = v;
        }

        // ---- prefetch next step's cur1 into the now-dead c1 registers ------
        const int win = (s < 6) ? widx_for(t, s + 1) : -1;
#pragma unroll
        for (int k = 0; k < 16; ++k) {
            c1a[k] = 0.f; c1b[k] = 0.f;
            if (win >= 0) {
                const float2 v = *(const float2*)
                    &CUR1[((size_t)win * BATCH + b0 + k) * H_DIM + i0];
                c1a[k] = v.x; c1b[k] = v.y;
            }
        }

        // ---- dense cur2: ascending h; 4 broadcast b128 + 2 float4 VMEM / j -
        float c2[8][4];
#pragma unroll
        for (int b = 0; b < 8; ++b)
#pragma unroll
            for (int r = 0; r < 4; ++r) c2[b][r] = 0.f;

#pragma unroll 8
        for (int j = 0; j < 64; ++j) {
            const float4 we4 = *(const float4*)&Wh0Q[((size_t)(j * 32 + q)) * 8];
            const float4 wo4 = *(const float4*)&Wh0Q[((size_t)(j * 32 + q)) * 8 + 4];
            const int jb = j * 32, jx = (j & 7) << 2;
            // this lane's 8-b strip: se chunks 2g,2g+1; so chunks 2g+4,2g+5
            const float4 E0 = *(const float4*)&sfw[jb + (((2*g    ) << 2) ^ jx)];
            const float4 E1 = *(const float4*)&sfw[jb + (((2*g + 1) << 2) ^ jx)];
            const float4 O0 = *(const float4*)&sfw[jb + (((2*g + 4) << 2) ^ jx)];
            const float4 O1 = *(const float4*)&sfw[jb + (((2*g + 5) << 2) ^ jx)];
            const float sevj[8] = {E0.x,E0.y,E0.z,E0.w, E1.x,E1.y,E1.z,E1.w};
            const float sovj[8] = {O0.x,O0.y,O0.z,O0.w, O1.x,O1.y,O1.z,O1.w};
            const float wev[4] = {we4.x, we4.y, we4.z, we4.w};
            const float wov[4] = {wo4.x, wo4.y, wo4.z, wo4.w};
#pragma unroll
            for (int b = 0; b < 8; ++b) {
#pragma unroll
                for (int r = 0; r < 4; ++r) {
                    c2[b][r] = __fmaf_rn(sevj[b], wev[r], c2[b][r]);   // h = 2j
                    c2[b][r] = __fmaf_rn(sovj[b], wov[r], c2[b][r]);   // h = 2j+1
                }
            }
        }

        // ---- mem2 + spikes (exact) and linear output tail (relaxed) --------
#pragma unroll
        for (int b = 0; b < 8; ++b) {
            float p0 = 0.f, p1 = 0.f;
#pragma unroll
            for (int r = 0; r < 4; ++r) {
                m2[b][r] = s2[b][r] ? 0.f
                         : __fadd_rn(__fmul_rn(0.9f, m2[b][r]), c2[b][r]);
                s2[b][r] = m2[b][r] > 0.5f;
                p0 += s2[b][r] ? ((const float*)&wex4)[r] : 0.f;
                p1 += s2[b][r] ? ((const float*)&wey4)[r] : 0.f;
            }
            po0[b] = __fmaf_rn(0.9f, po0[b], p0);       // mem_out linear: order-safe
            po1[b] = __fmaf_rn(0.9f, po1[b], p1);
        }
    }

    // ---- reduce per-lane output partials over the 32-lane i-groups ----------
#pragma unroll
    for (int b = 0; b < 8; ++b) {
        float r0 = po0[b], r1 = po1[b];
#pragma unroll
        for (int off = 16; off > 0; off >>= 1) {
            r0 += __shfl_xor(r0, off);
            r1 += __shfl_xor(r1, off);
        }
        if (q == 0) {
            float2 o;
            o.x = __fmul_rn(r0, vx);
            o.y = __fmul_rn(r1, vy);
            *(float2*)(out + ((size_t)t * BATCH + b0 + g * 8 + b) * 2) = o;
        }
    }
}

// ---------------------------------------------------------------------------
extern "C" void kernel_launch(void* const* d_in, const int* in_sizes, int n_in,
                              void* d_out, int out_size, void* d_ws, size_t ws_size,
                              hipStream_t stream) {
    const float* x    = (const float*)d_in[0];   // (128,1024,96)
    const float* Win  = (const float*)d_in[1];   // (128,96)
    const float* Wh0  = (const float*)d_in[2];   // (128,128)
    const float* Wout = (const float*)d_in[3];   // (2,128)
    const float* vx   = (const float*)d_in[4];   // (1,)
    const float* vy   = (const float*)d_in[5];   // (1,)
    float* out  = (float*)d_out;                 // (128,1024,2)

    // workspace: CUR1 (85.5 MB) | WS (64.1 MB) | WinT (48 KB) | Wh0Q (64 KB)
    float* CUR1 = (float*)d_ws;
    float* WS   = CUR1 + (size_t)NWIN * BATCH * H_DIM;
    float* WinT = WS   + (size_t)NWIN * BATCH * D_INPUT;
    float* Wh0Q = WinT + (size_t)D_INPUT * H_DIM;

    kT_wint   <<<dim3(112),                 dim3(256), 0, stream>>>(Win, Wh0, WinT, Wh0Q);
    kA0_winsum<<<dim3(BD / 256),            dim3(256), 0, stream>>>(x, WS);
    kA_wincur <<<dim3(NWIN, BATCH / 32),    dim3(256), 0, stream>>>(WS, WinT, CUR1);
    kB_snn    <<<dim3(BATCH / 128, T_STEPS), dim3(512), 0, stream>>>(CUR1, Wh0Q, Wout, vx, vy, out);
}